// Round 1
// baseline (12211.268 us; speedup 1.0000x reference)
//
#include <hip/hip_runtime.h>
#include <hip/hip_bf16.h>

#define T_SEQ 512
#define BATCH 64
#define IN0   128
#define HID   512
#define OUTF  256
#define G4    (4*HID)     // 2048 gate rows
#define NWG_REC 128       // persistent workgroups for recurrent kernels

typedef __attribute__((ext_vector_type(8))) short short8;   // 8 bf16 (MFMA A/B frag)
typedef __attribute__((ext_vector_type(4))) float f32x4;    // MFMA C/D frag

typedef unsigned short u16;

__device__ __forceinline__ float sigmoidf_(float x) { return 1.f / (1.f + __expf(-x)); }
__device__ __forceinline__ float tanhf_(float x)    { return 1.f - 2.f / (1.f + __expf(2.f * x)); }

__device__ __forceinline__ u16 f2bf(float f) {
    union { float f; unsigned u; } a; a.f = f;
    unsigned u = a.u;
    unsigned r = (u + 0x7fffu + ((u >> 16) & 1u)) >> 16;   // RNE
    return (u16)r;
}

// ---------------- f32 -> bf16 conversion (vectorized) ----------------
__global__ void cvt_f32_bf16(const float* __restrict__ in, u16* __restrict__ out, int n4) {
    int i = blockIdx.x * blockDim.x + threadIdx.x;
    if (i < n4) {
        float4 v = reinterpret_cast<const float4*>(in)[i];
        ushort4 o;
        o.x = f2bf(v.x); o.y = f2bf(v.y); o.z = f2bf(v.z); o.w = f2bf(v.w);
        reinterpret_cast<ushort4*>(out)[i] = o;
    }
}

// ---------------- persistent LSTM layer kernel ----------------
// Grid: 128 WGs x 256 thr. WG k owns hidden units [4k, 4k+4): 16 gate rows
// (order q = gate*4 + unit, gates i,f,g,o). Weights pre-packed in LDS in MFMA
// fragment order: slot s (=kq*16+q) holds 8 bf16 of row q at k = ks*32+kq*8.
template<int KIN>
__global__ __launch_bounds__(256, 1)
void lstm_layer(const u16* __restrict__ xin,   // [T,B,KIN] bf16 input sequence
                const u16* __restrict__ wih,   // [G4,KIN] bf16
                const u16* __restrict__ whh,   // [G4,HID] bf16
                const float* __restrict__ bias,// [G4] f32 (b_ih + b_hh)
                u16* __restrict__ yout,        // [T,B,HID] bf16 (also h state)
                float* __restrict__ hN, float* __restrict__ cN,  // [B,HID] f32
                unsigned* __restrict__ ctr)
{
    constexpr int KS_IN = KIN / 32;
    __shared__ __align__(16) u16 lds_whh[16][64 * 8];
    __shared__ __align__(16) u16 lds_wih[KS_IN][64 * 8];
    __shared__ float lds_gates[BATCH][17];    // +1 pad: conflict-free
    __shared__ float lds_bias[16];

    const int tid  = threadIdx.x;
    const int wg   = blockIdx.x;        // hidden units 4wg .. 4wg+3
    const int lane = tid & 63;
    const int w    = tid >> 6;          // wave id: batch rows 16w..16w+15

    if (tid < 16) lds_bias[tid] = bias[(tid >> 2) * HID + 4 * wg + (tid & 3)];

    for (int idx = tid; idx < 16 * 64; idx += 256) {
        int ks = idx >> 6, s = idx & 63, q = s & 15, kq = s >> 4;
        int r = (q >> 2) * HID + 4 * wg + (q & 3);
        *reinterpret_cast<uint4*>(&lds_whh[ks][s * 8]) =
            *reinterpret_cast<const uint4*>(&whh[(size_t)r * HID + ks * 32 + kq * 8]);
    }
    for (int idx = tid; idx < KS_IN * 64; idx += 256) {
        int ks = idx >> 6, s = idx & 63, q = s & 15, kq = s >> 4;
        int r = (q >> 2) * HID + 4 * wg + (q & 3);
        *reinterpret_cast<uint4*>(&lds_wih[ks][s * 8]) =
            *reinterpret_cast<const uint4*>(&wih[(size_t)r * KIN + ks * 32 + kq * 8]);
    }
    __syncthreads();

    const int pb = tid & 63;   // pointwise: batch index
    const int pu = tid >> 6;   // pointwise: unit index (0..3)
    float c = 0.f;
    unsigned target = 0;

    for (int t = 0; t < T_SEQ; ++t) {
        f32x4 acc = {0.f, 0.f, 0.f, 0.f};
        // input contribution: x[t] @ W_ih^T  (K = KIN)
        {
            const u16* arow = xin + ((size_t)t * BATCH + 16 * w + (lane & 15)) * KIN
                                  + ((lane >> 4) * 8);
            #pragma unroll
            for (int ks = 0; ks < KS_IN; ++ks) {
                short8 a = *reinterpret_cast<const short8*>(arow + ks * 32);
                short8 b = *reinterpret_cast<const short8*>(&lds_wih[ks][lane * 8]);
                acc = __builtin_amdgcn_mfma_f32_16x16x32_bf16(a, b, acc, 0, 0, 0);
            }
        }
        // recurrent contribution: h[t-1] @ W_hh^T  (K = 512); h[-1] = 0
        if (t > 0) {
            const u16* hrow = yout + ((size_t)(t - 1) * BATCH + 16 * w + (lane & 15)) * HID
                                   + ((lane >> 4) * 8);
            #pragma unroll
            for (int ks = 0; ks < 16; ++ks) {
                short8 a = *reinterpret_cast<const short8*>(hrow + ks * 32);
                short8 b = *reinterpret_cast<const short8*>(&lds_whh[ks][lane * 8]);
                acc = __builtin_amdgcn_mfma_f32_16x16x32_bf16(a, b, acc, 0, 0, 0);
            }
        }
        // D frag: row = 16w + (lane>>4)*4 + j (batch), col = lane&15 (q)
        #pragma unroll
        for (int j = 0; j < 4; ++j)
            lds_gates[16 * w + (lane >> 4) * 4 + j][lane & 15] = acc[j];
        __syncthreads();

        // pointwise LSTM cell update (f32). q = gate*4 + unit.
        float gi = sigmoidf_(lds_gates[pb][pu]      + lds_bias[pu]);
        float gf = sigmoidf_(lds_gates[pb][4 + pu]  + lds_bias[4 + pu]);
        float gg = tanhf_(   lds_gates[pb][8 + pu]  + lds_bias[8 + pu]);
        float go = sigmoidf_(lds_gates[pb][12 + pu] + lds_bias[12 + pu]);
        c = gf * c + gi * gg;
        float h = go * tanhf_(c);
        yout[((size_t)t * BATCH + pb) * HID + 4 * wg + pu] = f2bf(h);
        if (t == T_SEQ - 1) {
            hN[pb * HID + 4 * wg + pu] = h;
            cN[pb * HID + 4 * wg + pu] = c;
        }

        // grid barrier (all WGs co-resident: 128 WGs <= 256 CUs)
        if (t < T_SEQ - 1) {
            __syncthreads();
            target += NWG_REC;
            if (tid == 0) {
                __hip_atomic_fetch_add(ctr, 1u, __ATOMIC_RELEASE, __HIP_MEMORY_SCOPE_AGENT);
                while (__hip_atomic_load(ctr, __ATOMIC_ACQUIRE, __HIP_MEMORY_SCOPE_AGENT) < target)
                    __builtin_amdgcn_s_sleep(1);
            }
            __syncthreads();
        }
    }
}

// ---------------- final FC: out[32768,256] = y1[32768,512] @ fc_w[256,512]^T + b ---------
__global__ __launch_bounds__(256)
void fc_kernel(const u16* __restrict__ y1, const u16* __restrict__ fcw,
               const float* __restrict__ fcb, float* __restrict__ out)
{
    const int tid  = threadIdx.x;
    const int lane = tid & 63;
    const int wgid = blockIdx.x * 4 + (tid >> 6);  // 0..1023 waves
    const int nq   = wgid & 3;                     // 64-col block
    const int mt0  = wgid >> 2;                    // 0..255

    for (int j = 0; j < 8; ++j) {
        int mt = mt0 + j * 256;                    // M-tile 0..2047
        f32x4 acc[4] = {{0,0,0,0},{0,0,0,0},{0,0,0,0},{0,0,0,0}};
        const u16* arow = y1 + ((size_t)mt * 16 + (lane & 15)) * HID + (lane >> 4) * 8;
        #pragma unroll
        for (int ks = 0; ks < 16; ++ks) {
            short8 a = *reinterpret_cast<const short8*>(arow + ks * 32);
            #pragma unroll
            for (int nt = 0; nt < 4; ++nt) {
                const u16* brow = fcw + ((size_t)(nq * 64 + nt * 16 + (lane & 15))) * HID
                                      + ks * 32 + (lane >> 4) * 8;
                short8 b = *reinterpret_cast<const short8*>(brow);
                acc[nt] = __builtin_amdgcn_mfma_f32_16x16x32_bf16(a, b, acc[nt], 0, 0, 0);
            }
        }
        #pragma unroll
        for (int nt = 0; nt < 4; ++nt) {
            int col = nq * 64 + nt * 16 + (lane & 15);
            float bb = fcb[col];
            #pragma unroll
            for (int jj = 0; jj < 4; ++jj) {
                int row = mt * 16 + (lane >> 4) * 4 + jj;
                out[(size_t)row * OUTF + col] = acc[nt][jj] + bb;
            }
        }
    }
}

extern "C" void kernel_launch(void* const* d_in, const int* in_sizes, int n_in,
                              void* d_out, int out_size, void* d_ws, size_t ws_size,
                              hipStream_t stream)
{
    const float* x    = (const float*)d_in[0];
    const float* wih0 = (const float*)d_in[1];
    const float* whh0 = (const float*)d_in[2];
    const float* b0   = (const float*)d_in[3];
    const float* wih1 = (const float*)d_in[4];
    const float* whh1 = (const float*)d_in[5];
    const float* b1   = (const float*)d_in[6];
    const float* fcw  = (const float*)d_in[7];
    const float* fcb  = (const float*)d_in[8];
    float* out = (float*)d_out;

    char* ws = (char*)d_ws;
    size_t off = 0;
    unsigned* ctr = (unsigned*)ws;                    off += 256;
    u16* x_bf    = (u16*)(ws + off);                  off += (size_t)T_SEQ * BATCH * IN0 * 2;
    u16* wih0_bf = (u16*)(ws + off);                  off += (size_t)G4 * IN0 * 2;
    u16* whh0_bf = (u16*)(ws + off);                  off += (size_t)G4 * HID * 2;
    u16* wih1_bf = (u16*)(ws + off);                  off += (size_t)G4 * HID * 2;
    u16* whh1_bf = (u16*)(ws + off);                  off += (size_t)G4 * HID * 2;
    u16* fcw_bf  = (u16*)(ws + off);                  off += (size_t)OUTF * HID * 2;
    u16* y0      = (u16*)(ws + off);                  off += (size_t)T_SEQ * BATCH * HID * 2;
    u16* y1      = (u16*)(ws + off);                  off += (size_t)T_SEQ * BATCH * HID * 2;

    hipMemsetAsync(ctr, 0, 256, stream);

    auto conv = [&](const float* in, u16* o, int n) {
        int n4 = n / 4;
        cvt_f32_bf16<<<(n4 + 255) / 256, 256, 0, stream>>>(in, o, n4);
    };
    conv(x,    x_bf,    T_SEQ * BATCH * IN0);
    conv(wih0, wih0_bf, G4 * IN0);
    conv(whh0, whh0_bf, G4 * HID);
    conv(wih1, wih1_bf, G4 * HID);
    conv(whh1, whh1_bf, G4 * HID);
    conv(fcw,  fcw_bf,  OUTF * HID);

    float* outFC = out;
    float* hN0 = out + (size_t)T_SEQ * BATCH * OUTF;
    float* hN1 = hN0 + BATCH * HID;
    float* cN0 = hN1 + BATCH * HID;
    float* cN1 = cN0 + BATCH * HID;

    lstm_layer<IN0><<<NWG_REC, 256, 0, stream>>>(x_bf, wih0_bf, whh0_bf, b0, y0, hN0, cN0, ctr + 0);
    lstm_layer<HID><<<NWG_REC, 256, 0, stream>>>(y0,   wih1_bf, whh1_bf, b1, y1, hN1, cN1, ctr + 32);
    fc_kernel<<<256, 256, 0, stream>>>(y1, fcw_bf, fcb, outFC);
}

// Round 2
// 9513.504 us; speedup vs baseline: 1.2836x; 1.2836x over previous
//
#include <hip/hip_runtime.h>
#include <hip/hip_bf16.h>

#define T_SEQ 512
#define BATCH 64
#define IN0   128
#define HID   512
#define OUTF  256
#define G4    (4*HID)     // 2048 gate rows
#define NWG_L 128         // workgroups per layer (each owns 4 hidden units)

typedef __attribute__((ext_vector_type(8))) short short8;   // 8 bf16 (MFMA A/B frag)
typedef __attribute__((ext_vector_type(4))) float f32x4;    // MFMA C/D frag
typedef unsigned short u16;

__device__ __forceinline__ float sigmoidf_(float x) { return 1.f / (1.f + __expf(-x)); }
__device__ __forceinline__ float tanhf_(float x)    { return 1.f - 2.f / (1.f + __expf(2.f * x)); }

__device__ __forceinline__ u16 f2bf(float f) {
    union { float f; unsigned u; } a; a.f = f;
    unsigned u = a.u;
    return (u16)((u + 0x7fffu + ((u >> 16) & 1u)) >> 16);   // RNE
}

// Relaxed-agent spin (sc1 loads read coherence point, no per-poll invalidate).
// Periodic acquire as a progress guarantee; caller does the real acquire fence after.
__device__ __forceinline__ void spin_ge(unsigned* a, unsigned tgt) {
    unsigned it = 0;
    while (__hip_atomic_load(a, __ATOMIC_RELAXED, __HIP_MEMORY_SCOPE_AGENT) < tgt) {
        __builtin_amdgcn_s_sleep(2);
        if ((++it & 2047u) == 0u)
            (void)__hip_atomic_load(a, __ATOMIC_ACQUIRE, __HIP_MEMORY_SCOPE_AGENT);
    }
}

// ---------------- f32 -> bf16 conversion ----------------
__global__ void cvt_f32_bf16(const float* __restrict__ in, u16* __restrict__ out, int n4) {
    int i = blockIdx.x * blockDim.x + threadIdx.x;
    if (i < n4) {
        float4 v = reinterpret_cast<const float4*>(in)[i];
        ushort4 o;
        o.x = f2bf(v.x); o.y = f2bf(v.y); o.z = f2bf(v.z); o.w = f2bf(v.w);
        reinterpret_cast<ushort4*>(out)[i] = o;
    }
}

// ---------------- fused pipelined 2-layer LSTM ----------------
// WG g (0..127): layer 0, owns hidden units [4g,4g+4) -> 16 gate rows (cols q = gate*4+u).
// WG 128+g:      layer 1, same ownership.
// Flags: arrive0/arrive1 count completed (WG,step) events per layer.
// L0 step t: x[t] GEMM (no dep) -> wait arrive0>=t*128 -> h0[t-1] GEMM -> cell -> publish arrive0.
// L1 step t: wait arrive1>=t*128 -> h1[t-1] GEMM -> wait arrive0>=(t+1)*128 -> y0[t] GEMM -> cell -> publish arrive1.
template<int LAYER>
__device__ __forceinline__ void run_layer(
    const u16* __restrict__ asrc,   // L0: x_bf [T,B,128]; L1: y0 [T,B,512]
    const u16* __restrict__ wih, const u16* __restrict__ whh,
    const float* __restrict__ bias,
    u16* __restrict__ ybuf,         // own-layer h/y storage [T,B,512]
    float* __restrict__ hNout, float* __restrict__ cNout,
    unsigned* __restrict__ arr_own, unsigned* __restrict__ arr_dep,
    int g,
    u16 (*lds_w)[64 * 8], float (*lds_g)[17], float* lds_b)
{
    constexpr int KIN = (LAYER == 0) ? IN0 : HID;
    constexpr int KS1 = KIN / 32;        // input-part K slices
    constexpr int KS  = KS1 + 16;        // + recurrent K slices

    const int tid  = threadIdx.x;
    const int lane = tid & 63;
    const int w    = tid >> 6;           // wave id -> batch rows 16w..16w+15
    const int ubase = 4 * g;

    // ---- pack weights into LDS in MFMA B-frag order ----
    for (int idx = tid; idx < KS * 64; idx += 256) {
        int ks = idx >> 6, s = idx & 63, q = s & 15, kq = s >> 4;
        int r = (q >> 2) * HID + ubase + (q & 3);   // global gate row
        const u16* src;
        if (ks < KS1) src = wih + (size_t)r * KIN + ks * 32 + kq * 8;
        else          src = whh + (size_t)r * HID + (ks - KS1) * 32 + kq * 8;
        *reinterpret_cast<uint4*>(&lds_w[ks][s * 8]) = *reinterpret_cast<const uint4*>(src);
    }
    if (tid < 16) lds_b[tid] = bias[(tid >> 2) * HID + ubase + (tid & 3)];
    __syncthreads();

    const int pb = tid & 63;   // pointwise: batch index
    const int pu = tid >> 6;   // pointwise: unit index (0..3)
    float c = 0.f;

    const int arow = 16 * w + (lane & 15);
    const int koff = (lane >> 4) * 8;

    for (int t = 0; t < T_SEQ; ++t) {
        f32x4 ac[4] = {{0,0,0,0},{0,0,0,0},{0,0,0,0},{0,0,0,0}};

        if (LAYER == 0) {
            // phase 1: x[t] contribution — no dependency, runs before any wait
            const u16* ap = asrc + ((size_t)t * BATCH + arow) * KIN + koff;
            short8 areg[KS1];
            #pragma unroll
            for (int ks = 0; ks < KS1; ++ks)
                areg[ks] = *reinterpret_cast<const short8*>(ap + ks * 32);
            #pragma unroll
            for (int ks = 0; ks < KS1; ++ks) {
                short8 b = *reinterpret_cast<const short8*>(&lds_w[ks][lane * 8]);
                ac[ks & 3] = __builtin_amdgcn_mfma_f32_16x16x32_bf16(areg[ks], b, ac[ks & 3], 0, 0, 0);
            }
        }

        // phase 2: own-layer recurrent h[t-1] contribution
        if (t > 0) {
            if (tid == 0) {
                spin_ge(arr_own, (unsigned)t * NWG_L);
                __builtin_amdgcn_fence(__ATOMIC_ACQUIRE, "agent");
            }
            __syncthreads();
            const u16* hp = ybuf + ((size_t)(t - 1) * BATCH + arow) * HID + koff;
            short8 areg[16];
            #pragma unroll
            for (int ks = 0; ks < 16; ++ks)
                areg[ks] = *reinterpret_cast<const short8*>(hp + ks * 32);
            #pragma unroll
            for (int ks = 0; ks < 16; ++ks) {
                short8 b = *reinterpret_cast<const short8*>(&lds_w[KS1 + ks][lane * 8]);
                ac[ks & 3] = __builtin_amdgcn_mfma_f32_16x16x32_bf16(areg[ks], b, ac[ks & 3], 0, 0, 0);
            }
        }

        // phase 3 (L1 only): y0[t] contribution
        if (LAYER == 1) {
            if (tid == 0) {
                spin_ge(arr_dep, (unsigned)(t + 1) * NWG_L);
                __builtin_amdgcn_fence(__ATOMIC_ACQUIRE, "agent");
            }
            __syncthreads();
            const u16* ap = asrc + ((size_t)t * BATCH + arow) * HID + koff;
            short8 areg[16];
            #pragma unroll
            for (int ks = 0; ks < 16; ++ks)
                areg[ks] = *reinterpret_cast<const short8*>(ap + ks * 32);
            #pragma unroll
            for (int ks = 0; ks < 16; ++ks) {
                short8 b = *reinterpret_cast<const short8*>(&lds_w[ks][lane * 8]);
                ac[ks & 3] = __builtin_amdgcn_mfma_f32_16x16x32_bf16(areg[ks], b, ac[ks & 3], 0, 0, 0);
            }
        }

        f32x4 acc = (ac[0] + ac[1]) + (ac[2] + ac[3]);
        // D frag: row = 16w + (lane>>4)*4 + j (batch), col = lane&15 (q)
        #pragma unroll
        for (int j = 0; j < 4; ++j)
            lds_g[16 * w + (lane >> 4) * 4 + j][lane & 15] = acc[j];
        __syncthreads();

        // cell update (f32). q = gate*4 + unit.
        float gi = sigmoidf_(lds_g[pb][pu]      + lds_b[pu]);
        float gf = sigmoidf_(lds_g[pb][4 + pu]  + lds_b[4 + pu]);
        float gg = tanhf_(   lds_g[pb][8 + pu]  + lds_b[8 + pu]);
        float go = sigmoidf_(lds_g[pb][12 + pu] + lds_b[12 + pu]);
        c = gf * c + gi * gg;
        float h = go * tanhf_(c);
        ybuf[((size_t)t * BATCH + pb) * HID + ubase + pu] = f2bf(h);
        if (t == T_SEQ - 1) {
            hNout[pb * HID + ubase + pu] = h;
            cNout[pb * HID + ubase + pu] = c;
        }
        __syncthreads();   // all y stores drained (compiler emits vmcnt(0) before barrier)

        if (tid == 0) {
            __builtin_amdgcn_fence(__ATOMIC_RELEASE, "agent");   // one wbl2 per WG per step
            __hip_atomic_fetch_add(arr_own, 1u, __ATOMIC_RELAXED, __HIP_MEMORY_SCOPE_AGENT);
        }
    }
}

__global__ __launch_bounds__(256, 1)
void lstm_fused(const u16* __restrict__ x_bf,
                const u16* __restrict__ wih0, const u16* __restrict__ whh0, const float* __restrict__ b0,
                const u16* __restrict__ wih1, const u16* __restrict__ whh1, const float* __restrict__ b1,
                u16* __restrict__ y0, u16* __restrict__ y1,
                float* __restrict__ hN, float* __restrict__ cN,
                unsigned* __restrict__ ctr)
{
    __shared__ __align__(16) u16 lds_w[32][64 * 8];   // 32 KB (max of both layers)
    __shared__ float lds_g[BATCH][17];
    __shared__ float lds_b[16];

    const int wgid = blockIdx.x;
    if (wgid < NWG_L) {
        run_layer<0>(x_bf, wih0, whh0, b0, y0, hN, cN,
                     ctr + 0, ctr + 0, wgid, lds_w, lds_g, lds_b);
    } else {
        run_layer<1>(y0, wih1, whh1, b1, y1, hN + BATCH * HID, cN + BATCH * HID,
                     ctr + 32, ctr + 0, wgid - NWG_L, lds_w, lds_g, lds_b);
    }
}

// ---------------- final FC: out[32768,256] = y1[32768,512] @ fc_w[256,512]^T + b ----------
__global__ __launch_bounds__(256)
void fc_kernel(const u16* __restrict__ y1, const u16* __restrict__ fcw,
               const float* __restrict__ fcb, float* __restrict__ out)
{
    const int tid  = threadIdx.x;
    const int lane = tid & 63;
    const int wgid = blockIdx.x * 4 + (tid >> 6);  // 0..1023 waves
    const int nq   = wgid & 3;                     // 64-col block
    const int mt0  = wgid >> 2;                    // 0..255

    for (int j = 0; j < 8; ++j) {
        int mt = mt0 + j * 256;                    // M-tile 0..2047
        f32x4 acc[4] = {{0,0,0,0},{0,0,0,0},{0,0,0,0},{0,0,0,0}};
        const u16* arow = y1 + ((size_t)mt * 16 + (lane & 15)) * HID + (lane >> 4) * 8;
        #pragma unroll
        for (int ks = 0; ks < 16; ++ks) {
            short8 a = *reinterpret_cast<const short8*>(arow + ks * 32);
            #pragma unroll
            for (int nt = 0; nt < 4; ++nt) {
                const u16* brow = fcw + ((size_t)(nq * 64 + nt * 16 + (lane & 15))) * HID
                                      + ks * 32 + (lane >> 4) * 8;
                short8 b = *reinterpret_cast<const short8*>(brow);
                acc[nt] = __builtin_amdgcn_mfma_f32_16x16x32_bf16(a, b, acc[nt], 0, 0, 0);
            }
        }
        #pragma unroll
        for (int nt = 0; nt < 4; ++nt) {
            int col = nq * 64 + nt * 16 + (lane & 15);
            float bb = fcb[col];
            #pragma unroll
            for (int jj = 0; jj < 4; ++jj) {
                int row = mt * 16 + (lane >> 4) * 4 + jj;
                out[(size_t)row * OUTF + col] = acc[nt][jj] + bb;
            }
        }
    }
}

extern "C" void kernel_launch(void* const* d_in, const int* in_sizes, int n_in,
                              void* d_out, int out_size, void* d_ws, size_t ws_size,
                              hipStream_t stream)
{
    const float* x    = (const float*)d_in[0];
    const float* wih0 = (const float*)d_in[1];
    const float* whh0 = (const float*)d_in[2];
    const float* b0   = (const float*)d_in[3];
    const float* wih1 = (const float*)d_in[4];
    const float* whh1 = (const float*)d_in[5];
    const float* b1   = (const float*)d_in[6];
    const float* fcw  = (const float*)d_in[7];
    const float* fcb  = (const float*)d_in[8];
    float* out = (float*)d_out;

    char* ws = (char*)d_ws;
    size_t off = 0;
    unsigned* ctr = (unsigned*)ws;                    off += 256;
    u16* x_bf    = (u16*)(ws + off);                  off += (size_t)T_SEQ * BATCH * IN0 * 2;
    u16* wih0_bf = (u16*)(ws + off);                  off += (size_t)G4 * IN0 * 2;
    u16* whh0_bf = (u16*)(ws + off);                  off += (size_t)G4 * HID * 2;
    u16* wih1_bf = (u16*)(ws + off);                  off += (size_t)G4 * HID * 2;
    u16* whh1_bf = (u16*)(ws + off);                  off += (size_t)G4 * HID * 2;
    u16* fcw_bf  = (u16*)(ws + off);                  off += (size_t)OUTF * HID * 2;
    u16* y0      = (u16*)(ws + off);                  off += (size_t)T_SEQ * BATCH * HID * 2;
    u16* y1      = (u16*)(ws + off);                  off += (size_t)T_SEQ * BATCH * HID * 2;

    hipMemsetAsync(ctr, 0, 256, stream);

    auto conv = [&](const float* in, u16* o, int n) {
        int n4 = n / 4;
        cvt_f32_bf16<<<(n4 + 255) / 256, 256, 0, stream>>>(in, o, n4);
    };
    conv(x,    x_bf,    T_SEQ * BATCH * IN0);
    conv(wih0, wih0_bf, G4 * IN0);
    conv(whh0, whh0_bf, G4 * HID);
    conv(wih1, wih1_bf, G4 * HID);
    conv(whh1, whh1_bf, G4 * HID);
    conv(fcw,  fcw_bf,  OUTF * HID);

    float* outFC = out;
    float* hN = out + (size_t)T_SEQ * BATCH * OUTF;     // [2,B,H]
    float* cN = hN + 2 * BATCH * HID;                   // [2,B,H]

    lstm_fused<<<2 * NWG_L, 256, 0, stream>>>(x_bf, wih0_bf, whh0_bf, b0,
                                              wih1_bf, whh1_bf, b1,
                                              y0, y1, hN, cN, ctr);
    fc_kernel<<<256, 256, 0, stream>>>(y1, fcw_bf, fcb, outFC);
}

// Round 3
// 4456.523 us; speedup vs baseline: 2.7401x; 2.1347x over previous
//
#include <hip/hip_runtime.h>
#include <hip/hip_bf16.h>

#define T_SEQ 512
#define BATCH 64
#define IN0   128
#define HID   512
#define OUTF  256
#define G4    (4*HID)     // 2048 gate rows
#define NWG_L 64          // workgroups per layer (each owns 8 hidden units)

typedef __attribute__((ext_vector_type(8))) short short8;   // 8 bf16 (MFMA A/B frag)
typedef __attribute__((ext_vector_type(4))) float f32x4;    // MFMA C/D frag
typedef unsigned short u16;

__device__ __forceinline__ float sigmoidf_(float x) { return 1.f / (1.f + __expf(-x)); }
__device__ __forceinline__ float tanhf_(float x)    { return 1.f - 2.f / (1.f + __expf(2.f * x)); }

__device__ __forceinline__ u16 f2bf(float f) {
    union { float f; unsigned u; } a; a.f = f;
    unsigned u = a.u;
    return (u16)((u + 0x7fffu + ((u >> 16) & 1u)) >> 16);   // RNE
}

// Wave-0 poll: lane l watches flags[l]; exit when ALL 64 flags >= tgt.
// Relaxed agent atomic loads (sc1) read the coherence point directly —
// no buffer_inv, no wbl2, no RMW contention.
__device__ __forceinline__ void wave_poll_ge(unsigned* flags, int lane, unsigned tgt) {
    for (;;) {
        unsigned v = __hip_atomic_load(flags + lane, __ATOMIC_RELAXED, __HIP_MEMORY_SCOPE_AGENT);
        if (__all((int)(v >= tgt))) return;
        __builtin_amdgcn_s_sleep(1);
    }
}

// ---------------- f32 -> bf16 conversion ----------------
__global__ void cvt_f32_bf16(const float* __restrict__ in, u16* __restrict__ out, int n4) {
    int i = blockIdx.x * blockDim.x + threadIdx.x;
    if (i < n4) {
        float4 v = reinterpret_cast<const float4*>(in)[i];
        ushort4 o;
        o.x = f2bf(v.x); o.y = f2bf(v.y); o.z = f2bf(v.z); o.w = f2bf(v.w);
        reinterpret_cast<ushort4*>(out)[i] = o;
    }
}

// ---------------- fused pipelined 2-layer LSTM ----------------
// WG g in [0,64): layer 0, owns hidden units [8g, 8g+8) -> 32 gate rows as 2
// MFMA col-tiles (tile nt covers units 8g+4nt..+3, cols q = gate*4 + du).
// WG 64+g: layer 1, same ownership. flags0/flags1[g] = #steps completed.
template<int LAYER>
__device__ __forceinline__ void run_layer(
    const u16* __restrict__ asrc,   // L0: x_bf [T,B,128]; L1: y0 [T,B,512]
    const u16* __restrict__ wih, const u16* __restrict__ whh,
    const float* __restrict__ bias,
    u16* __restrict__ ybuf,         // own-layer h/y storage [T,B,512]
    float* __restrict__ hNout, float* __restrict__ cNout,
    unsigned* flags_own, unsigned* flags_dep, int g,
    u16 (*lds_w)[32][512], float (*lds_g)[33], float (*lds_b)[16])
{
    constexpr int KIN = (LAYER == 0) ? IN0 : HID;
    constexpr int KS1 = KIN / 32;        // input-part K slices
    constexpr int KS  = KS1 + 16;        // + recurrent K slices

    const int tid  = threadIdx.x;
    const int lane = tid & 63;
    const int w    = tid >> 6;           // wave id -> batch rows 16w..16w+15
    const int ubase = 8 * g;

    // ---- pack weights into LDS in MFMA B-frag order (2 col-tiles) ----
    for (int idx = tid; idx < 2 * KS * 64; idx += 256) {
        int nt  = (idx >= KS * 64) ? 1 : 0;
        int rem = idx - nt * KS * 64;
        int ks = rem >> 6, s = rem & 63, q = s & 15, kq = s >> 4;
        int r = (q >> 2) * HID + ubase + 4 * nt + (q & 3);   // global gate row
        const u16* src = (ks < KS1)
            ? wih + (size_t)r * KIN + (size_t)ks * 32 + kq * 8
            : whh + (size_t)r * HID + (size_t)(ks - KS1) * 32 + kq * 8;
        *reinterpret_cast<uint4*>(&lds_w[nt][ks][s * 8]) =
            *reinterpret_cast<const uint4*>(src);
    }
    if (tid < 32) {
        int nt = tid >> 4, q = tid & 15;
        lds_b[nt][q] = bias[(q >> 2) * HID + ubase + 4 * nt + (q & 3)];
    }
    __syncthreads();

    const int pb  = tid & 63;   // pointwise: batch index
    const int pu2 = tid >> 6;   // pointwise: unit-pair index (0..3)
    float c0 = 0.f, c1 = 0.f;

    const int arow = 16 * w + (lane & 15);
    const int koff = (lane >> 4) * 8;

    for (int t = 0; t < T_SEQ; ++t) {
        f32x4 ac0[4] = {{0,0,0,0},{0,0,0,0},{0,0,0,0},{0,0,0,0}};
        f32x4 ac1[4] = {{0,0,0,0},{0,0,0,0},{0,0,0,0},{0,0,0,0}};

        if (LAYER == 0) {
            // x[t] contribution — no dependency, runs before any wait
            const u16* ap = asrc + ((size_t)t * BATCH + arow) * KIN + koff;
            short8 a[KS1];
            #pragma unroll
            for (int j = 0; j < KS1; ++j)
                a[j] = *reinterpret_cast<const short8*>(ap + j * 32);
            #pragma unroll
            for (int j = 0; j < KS1; ++j) {
                ac0[j & 3] = __builtin_amdgcn_mfma_f32_16x16x32_bf16(
                    a[j], *reinterpret_cast<const short8*>(&lds_w[0][j][lane * 8]), ac0[j & 3], 0, 0, 0);
                ac1[j & 3] = __builtin_amdgcn_mfma_f32_16x16x32_bf16(
                    a[j], *reinterpret_cast<const short8*>(&lds_w[1][j][lane * 8]), ac1[j & 3], 0, 0, 0);
            }
        }

        // own-layer recurrent h[t-1] contribution
        if (t > 0) {
            if (w == 0) wave_poll_ge(flags_own, lane, (unsigned)t);
            __syncthreads();
            const u16* hp = ybuf + ((size_t)(t - 1) * BATCH + arow) * HID + koff;
            short8 a[16];
            #pragma unroll
            for (int j = 0; j < 16; ++j)
                a[j] = *reinterpret_cast<const short8*>(hp + j * 32);
            #pragma unroll
            for (int j = 0; j < 16; ++j) {
                ac0[j & 3] = __builtin_amdgcn_mfma_f32_16x16x32_bf16(
                    a[j], *reinterpret_cast<const short8*>(&lds_w[0][KS1 + j][lane * 8]), ac0[j & 3], 0, 0, 0);
                ac1[j & 3] = __builtin_amdgcn_mfma_f32_16x16x32_bf16(
                    a[j], *reinterpret_cast<const short8*>(&lds_w[1][KS1 + j][lane * 8]), ac1[j & 3], 0, 0, 0);
            }
        }

        // L1: y0[t] contribution (gated on layer-0 progress)
        if (LAYER == 1) {
            if (w == 0) wave_poll_ge(flags_dep, lane, (unsigned)(t + 1));
            __syncthreads();
            const u16* ap = asrc + ((size_t)t * BATCH + arow) * HID + koff;
            short8 a[16];
            #pragma unroll
            for (int j = 0; j < 16; ++j)
                a[j] = *reinterpret_cast<const short8*>(ap + j * 32);
            #pragma unroll
            for (int j = 0; j < 16; ++j) {
                ac0[j & 3] = __builtin_amdgcn_mfma_f32_16x16x32_bf16(
                    a[j], *reinterpret_cast<const short8*>(&lds_w[0][j][lane * 8]), ac0[j & 3], 0, 0, 0);
                ac1[j & 3] = __builtin_amdgcn_mfma_f32_16x16x32_bf16(
                    a[j], *reinterpret_cast<const short8*>(&lds_w[1][j][lane * 8]), ac1[j & 3], 0, 0, 0);
            }
        }

        f32x4 s0 = (ac0[0] + ac0[1]) + (ac0[2] + ac0[3]);
        f32x4 s1 = (ac1[0] + ac1[1]) + (ac1[2] + ac1[3]);
        // D frag: row = 16w + (lane>>4)*4 + j (batch), col = lane&15 (q)
        #pragma unroll
        for (int j = 0; j < 4; ++j) {
            int row = 16 * w + (lane >> 4) * 4 + j;
            lds_g[row][lane & 15]      = s0[j];
            lds_g[row][16 + (lane & 15)] = s1[j];
        }
        __syncthreads();

        // pointwise cell update (f32): thread (pb,pu2) owns units 2pu2, 2pu2+1
        {
            const int nt = pu2 >> 1;
            const int dq = (2 * pu2) & 3;       // 0 or 2; dq+1 pairs with it
            const float* gr = &lds_g[pb][nt * 16];
            const float* br = lds_b[nt];
            float gi0 = sigmoidf_(gr[dq]      + br[dq]);
            float gf0 = sigmoidf_(gr[4 + dq]  + br[4 + dq]);
            float gg0 = tanhf_(   gr[8 + dq]  + br[8 + dq]);
            float go0 = sigmoidf_(gr[12 + dq] + br[12 + dq]);
            c0 = gf0 * c0 + gi0 * gg0;
            float h0v = go0 * tanhf_(c0);
            float gi1 = sigmoidf_(gr[dq + 1]      + br[dq + 1]);
            float gf1 = sigmoidf_(gr[4 + dq + 1]  + br[4 + dq + 1]);
            float gg1 = tanhf_(   gr[8 + dq + 1]  + br[8 + dq + 1]);
            float go1 = sigmoidf_(gr[12 + dq + 1] + br[12 + dq + 1]);
            c1 = gf1 * c1 + gi1 * gg1;
            float h1v = go1 * tanhf_(c1);

            unsigned pack = (unsigned)f2bf(h0v) | ((unsigned)f2bf(h1v) << 16);
            unsigned* yp32 = reinterpret_cast<unsigned*>(ybuf)
                           + ((size_t)t * BATCH + pb) * (HID / 2) + (ubase + 2 * pu2) / 2;
            // relaxed agent atomic store: sc1 write-through to coherence point
            __hip_atomic_store(yp32, pack, __ATOMIC_RELAXED, __HIP_MEMORY_SCOPE_AGENT);

            if (t == T_SEQ - 1) {
                hNout[pb * HID + ubase + 2 * pu2]     = h0v;
                hNout[pb * HID + ubase + 2 * pu2 + 1] = h1v;
                cNout[pb * HID + ubase + 2 * pu2]     = c0;
                cNout[pb * HID + ubase + 2 * pu2 + 1] = c1;
            }
        }

        // drain own wave's stores, barrier (all WG stores at coherence point),
        // then publish progress with a single relaxed flag store (no RMW, no fence).
        asm volatile("s_waitcnt vmcnt(0)" ::: "memory");
        __syncthreads();
        if (tid == 0)
            __hip_atomic_store(flags_own + g, (unsigned)(t + 1),
                               __ATOMIC_RELAXED, __HIP_MEMORY_SCOPE_AGENT);
    }
}

__global__ __launch_bounds__(256, 1)
void lstm_fused(const u16* __restrict__ x_bf,
                const u16* __restrict__ wih0, const u16* __restrict__ whh0, const float* __restrict__ b0,
                const u16* __restrict__ wih1, const u16* __restrict__ whh1, const float* __restrict__ b1,
                u16* __restrict__ y0, u16* __restrict__ y1,
                float* __restrict__ hN, float* __restrict__ cN,
                unsigned* __restrict__ ctr)
{
    __shared__ __align__(16) u16 lds_w[2][32][512];   // 64 KB (L0 uses KS=20 of 32)
    __shared__ float lds_g[BATCH][33];                // 32 gate cols + pad
    __shared__ float lds_b[2][16];

    unsigned* flags0 = ctr;
    unsigned* flags1 = ctr + 64;

    const int wgid = blockIdx.x;
    if (wgid < NWG_L) {
        run_layer<0>(x_bf, wih0, whh0, b0, y0, hN, cN,
                     flags0, flags0, wgid, lds_w, lds_g, lds_b);
    } else {
        run_layer<1>(y0, wih1, whh1, b1, y1, hN + BATCH * HID, cN + BATCH * HID,
                     flags1, flags0, wgid - NWG_L, lds_w, lds_g, lds_b);
    }
}

// ---------------- final FC: out[32768,256] = y1[32768,512] @ fc_w[256,512]^T + b ----------
__global__ __launch_bounds__(256)
void fc_kernel(const u16* __restrict__ y1, const u16* __restrict__ fcw,
               const float* __restrict__ fcb, float* __restrict__ out)
{
    const int tid  = threadIdx.x;
    const int lane = tid & 63;
    const int wgid = blockIdx.x * 4 + (tid >> 6);  // 0..1023 waves
    const int nq   = wgid & 3;                     // 64-col block
    const int mt0  = wgid >> 2;                    // 0..255

    for (int j = 0; j < 8; ++j) {
        int mt = mt0 + j * 256;                    // M-tile 0..2047
        f32x4 acc[4] = {{0,0,0,0},{0,0,0,0},{0,0,0,0},{0,0,0,0}};
        const u16* arow = y1 + ((size_t)mt * 16 + (lane & 15)) * HID + (lane >> 4) * 8;
        #pragma unroll
        for (int ks = 0; ks < 16; ++ks) {
            short8 a = *reinterpret_cast<const short8*>(arow + ks * 32);
            #pragma unroll
            for (int nt = 0; nt < 4; ++nt) {
                const u16* brow = fcw + ((size_t)(nq * 64 + nt * 16 + (lane & 15))) * HID
                                      + ks * 32 + (lane >> 4) * 8;
                short8 b = *reinterpret_cast<const short8*>(brow);
                acc[nt] = __builtin_amdgcn_mfma_f32_16x16x32_bf16(a, b, acc[nt], 0, 0, 0);
            }
        }
        #pragma unroll
        for (int nt = 0; nt < 4; ++nt) {
            int col = nq * 64 + nt * 16 + (lane & 15);
            float bb = fcb[col];
            #pragma unroll
            for (int jj = 0; jj < 4; ++jj) {
                int row = mt * 16 + (lane >> 4) * 4 + jj;
                out[(size_t)row * OUTF + col] = acc[nt][jj] + bb;
            }
        }
    }
}

extern "C" void kernel_launch(void* const* d_in, const int* in_sizes, int n_in,
                              void* d_out, int out_size, void* d_ws, size_t ws_size,
                              hipStream_t stream)
{
    const float* x    = (const float*)d_in[0];
    const float* wih0 = (const float*)d_in[1];
    const float* whh0 = (const float*)d_in[2];
    const float* b0   = (const float*)d_in[3];
    const float* wih1 = (const float*)d_in[4];
    const float* whh1 = (const float*)d_in[5];
    const float* b1   = (const float*)d_in[6];
    const float* fcw  = (const float*)d_in[7];
    const float* fcb  = (const float*)d_in[8];
    float* out = (float*)d_out;

    char* ws = (char*)d_ws;
    size_t off = 0;
    unsigned* ctr = (unsigned*)ws;                    off += 512;   // flags0[64], flags1[64]
    u16* x_bf    = (u16*)(ws + off);                  off += (size_t)T_SEQ * BATCH * IN0 * 2;
    u16* wih0_bf = (u16*)(ws + off);                  off += (size_t)G4 * IN0 * 2;
    u16* whh0_bf = (u16*)(ws + off);                  off += (size_t)G4 * HID * 2;
    u16* wih1_bf = (u16*)(ws + off);                  off += (size_t)G4 * HID * 2;
    u16* whh1_bf = (u16*)(ws + off);                  off += (size_t)G4 * HID * 2;
    u16* fcw_bf  = (u16*)(ws + off);                  off += (size_t)OUTF * HID * 2;
    u16* y0      = (u16*)(ws + off);                  off += (size_t)T_SEQ * BATCH * HID * 2;
    u16* y1      = (u16*)(ws + off);                  off += (size_t)T_SEQ * BATCH * HID * 2;

    hipMemsetAsync(ctr, 0, 512, stream);

    auto conv = [&](const float* in, u16* o, int n) {
        int n4 = n / 4;
        cvt_f32_bf16<<<(n4 + 255) / 256, 256, 0, stream>>>(in, o, n4);
    };
    conv(x,    x_bf,    T_SEQ * BATCH * IN0);
    conv(wih0, wih0_bf, G4 * IN0);
    conv(whh0, whh0_bf, G4 * HID);
    conv(wih1, wih1_bf, G4 * HID);
    conv(whh1, whh1_bf, G4 * HID);
    conv(fcw,  fcw_bf,  OUTF * HID);

    float* outFC = out;
    float* hN = out + (size_t)T_SEQ * BATCH * OUTF;     // [2,B,H]
    float* cN = hN + 2 * BATCH * HID;                   // [2,B,H]

    lstm_fused<<<2 * NWG_L, 256, 0, stream>>>(x_bf, wih0_bf, whh0_bf, b0,
                                              wih1_bf, whh1_bf, b1,
                                              y0, y1, hN, cN, ctr);
    fc_kernel<<<256, 256, 0, stream>>>(y1, fcw_bf, fcb, outFC);
}

// Round 4
// 3669.393 us; speedup vs baseline: 3.3279x; 1.2145x over previous
//
#include <hip/hip_runtime.h>
#include <hip/hip_bf16.h>

#define T_SEQ 512
#define BATCH 64
#define IN0   128
#define HID   512
#define OUTF  256
#define G4    (4*HID)     // 2048 gate rows
#define NWG_L 64          // workgroups per layer (each owns 8 hidden units)
#define FLAG_STRIDE 32    // u32s between flags -> one 128B line per producer

typedef __attribute__((ext_vector_type(8))) short short8;   // 8 bf16 (MFMA A/B frag)
typedef __attribute__((ext_vector_type(4))) float f32x4;    // MFMA C/D frag
typedef unsigned short u16;

__device__ __forceinline__ float sigmoidf_(float x) { return 1.f / (1.f + __expf(-x)); }
__device__ __forceinline__ float tanhf_(float x)    { return 1.f - 2.f / (1.f + __expf(2.f * x)); }

__device__ __forceinline__ u16 f2bf(float f) {
    union { float f; unsigned u; } a; a.f = f;
    unsigned u = a.u;
    return (u16)((u + 0x7fffu + ((u >> 16) & 1u)) >> 16);   // RNE
}

// Wave poll: lane l watches flags[l*FLAG_STRIDE] (one line per producer, no
// hot-line contention). Relaxed agent loads read the coherence point without
// invalidating; rare acquire as progress safety net.
__device__ __forceinline__ void wave_poll_ge(unsigned* flags, int lane, unsigned tgt) {
    unsigned it = 0;
    for (;;) {
        unsigned v = __hip_atomic_load(flags + (size_t)lane * FLAG_STRIDE,
                                       __ATOMIC_RELAXED, __HIP_MEMORY_SCOPE_AGENT);
        if (__all((int)(v >= tgt))) return;
        __builtin_amdgcn_s_sleep(2);
        if ((++it & 2047u) == 0u)
            (void)__hip_atomic_load(flags, __ATOMIC_ACQUIRE, __HIP_MEMORY_SCOPE_AGENT);
    }
}

// ---------------- f32 -> bf16 conversion ----------------
__global__ void cvt_f32_bf16(const float* __restrict__ in, u16* __restrict__ out, int n4) {
    int i = blockIdx.x * blockDim.x + threadIdx.x;
    if (i < n4) {
        float4 v = reinterpret_cast<const float4*>(in)[i];
        ushort4 o;
        o.x = f2bf(v.x); o.y = f2bf(v.y); o.z = f2bf(v.z); o.w = f2bf(v.w);
        reinterpret_cast<ushort4*>(out)[i] = o;
    }
}

// ---------------- fused pipelined 2-layer LSTM ----------------
// WG g in [0,64): layer 0, owns hidden units [8g, 8g+8) -> 32 gate rows as 2
// MFMA col-tiles. WG 64+g: layer 1, same ownership.
// flags0/flags1[g*FLAG_STRIDE] = #steps completed by WG g of that layer.
template<int LAYER>
__device__ __forceinline__ void run_layer(
    const u16* __restrict__ asrc,   // L0: x_bf [T,B,128]; L1: y0 [T,B,512]
    const u16* __restrict__ wih, const u16* __restrict__ whh,
    const float* __restrict__ bias,
    u16* __restrict__ ybuf,         // own-layer h/y storage [T,B,512]
    float* __restrict__ hNout, float* __restrict__ cNout,
    unsigned* flags_own, unsigned* flags_dep, int g,
    u16 (*lds_w)[32][512], float (*lds_g)[33], float (*lds_b)[16])
{
    constexpr int KIN = (LAYER == 0) ? IN0 : HID;
    constexpr int KS1 = KIN / 32;        // input-part K slices
    constexpr int KS  = KS1 + 16;        // + recurrent K slices

    const int tid  = threadIdx.x;
    const int lane = tid & 63;
    const int w    = tid >> 6;           // wave id -> batch rows 16w..16w+15
    const int ubase = 8 * g;

    // ---- pack weights into LDS in MFMA B-frag order (2 col-tiles) ----
    for (int idx = tid; idx < 2 * KS * 64; idx += 256) {
        int nt  = (idx >= KS * 64) ? 1 : 0;
        int rem = idx - nt * KS * 64;
        int ks = rem >> 6, s = rem & 63, q = s & 15, kq = s >> 4;
        int r = (q >> 2) * HID + ubase + 4 * nt + (q & 3);   // global gate row
        const u16* src = (ks < KS1)
            ? wih + (size_t)r * KIN + (size_t)ks * 32 + kq * 8
            : whh + (size_t)r * HID + (size_t)(ks - KS1) * 32 + kq * 8;
        *reinterpret_cast<uint4*>(&lds_w[nt][ks][s * 8]) =
            *reinterpret_cast<const uint4*>(src);
    }
    if (tid < 32) {
        int nt = tid >> 4, q = tid & 15;
        lds_b[nt][q] = bias[(q >> 2) * HID + ubase + 4 * nt + (q & 3)];
    }
    __syncthreads();

    const int pb  = tid & 63;   // pointwise: batch index
    const int pu2 = tid >> 6;   // pointwise: unit-pair index (0..3)
    float c0 = 0.f, c1 = 0.f;

    const int arow = 16 * w + (lane & 15);
    const int koff = (lane >> 4) * 8;

    for (int t = 0; t < T_SEQ; ++t) {
        f32x4 ac0[4] = {{0,0,0,0},{0,0,0,0},{0,0,0,0},{0,0,0,0}};
        f32x4 ac1[4] = {{0,0,0,0},{0,0,0,0},{0,0,0,0},{0,0,0,0}};

        if (LAYER == 0) {
            // x[t] contribution — no dependency, runs before any wait
            const u16* ap = asrc + ((size_t)t * BATCH + arow) * KIN + koff;
            short8 a[KS1];
            #pragma unroll
            for (int j = 0; j < KS1; ++j)
                a[j] = *reinterpret_cast<const short8*>(ap + j * 32);
            #pragma unroll
            for (int j = 0; j < KS1; ++j) {
                ac0[j & 3] = __builtin_amdgcn_mfma_f32_16x16x32_bf16(
                    a[j], *reinterpret_cast<const short8*>(&lds_w[0][j][lane * 8]), ac0[j & 3], 0, 0, 0);
                ac1[j & 3] = __builtin_amdgcn_mfma_f32_16x16x32_bf16(
                    a[j], *reinterpret_cast<const short8*>(&lds_w[1][j][lane * 8]), ac1[j & 3], 0, 0, 0);
            }
        }

        // ---- waits: parallel polls on separate waves, one barrier join ----
        if (LAYER == 0) {
            if (t > 0) {
                if (w == 0) wave_poll_ge(flags_own, lane, (unsigned)t);
                __syncthreads();
            }
        } else {
            if (w == 0) wave_poll_ge(flags_own, lane, (unsigned)t);        // h1[t-1] ready
            if (w == 1) wave_poll_ge(flags_dep, lane, (unsigned)(t + 1));  // y0[t] ready
            __syncthreads();
        }

        // own-layer recurrent h[t-1] contribution
        if (t > 0) {
            const u16* hp = ybuf + ((size_t)(t - 1) * BATCH + arow) * HID + koff;
            short8 a[16];
            #pragma unroll
            for (int j = 0; j < 16; ++j)
                a[j] = *reinterpret_cast<const short8*>(hp + j * 32);
            #pragma unroll
            for (int j = 0; j < 16; ++j) {
                ac0[j & 3] = __builtin_amdgcn_mfma_f32_16x16x32_bf16(
                    a[j], *reinterpret_cast<const short8*>(&lds_w[0][KS1 + j][lane * 8]), ac0[j & 3], 0, 0, 0);
                ac1[j & 3] = __builtin_amdgcn_mfma_f32_16x16x32_bf16(
                    a[j], *reinterpret_cast<const short8*>(&lds_w[1][KS1 + j][lane * 8]), ac1[j & 3], 0, 0, 0);
            }
        }

        // L1: y0[t] contribution
        if (LAYER == 1) {
            const u16* ap = asrc + ((size_t)t * BATCH + arow) * HID + koff;
            short8 a[16];
            #pragma unroll
            for (int j = 0; j < 16; ++j)
                a[j] = *reinterpret_cast<const short8*>(ap + j * 32);
            #pragma unroll
            for (int j = 0; j < 16; ++j) {
                ac0[j & 3] = __builtin_amdgcn_mfma_f32_16x16x32_bf16(
                    a[j], *reinterpret_cast<const short8*>(&lds_w[0][j][lane * 8]), ac0[j & 3], 0, 0, 0);
                ac1[j & 3] = __builtin_amdgcn_mfma_f32_16x16x32_bf16(
                    a[j], *reinterpret_cast<const short8*>(&lds_w[1][j][lane * 8]), ac1[j & 3], 0, 0, 0);
            }
        }

        f32x4 s0 = (ac0[0] + ac0[1]) + (ac0[2] + ac0[3]);
        f32x4 s1 = (ac1[0] + ac1[1]) + (ac1[2] + ac1[3]);
        // D frag: row = 16w + (lane>>4)*4 + j (batch), col = lane&15 (q)
        #pragma unroll
        for (int j = 0; j < 4; ++j) {
            int row = 16 * w + (lane >> 4) * 4 + j;
            lds_g[row][lane & 15]        = s0[j];
            lds_g[row][16 + (lane & 15)] = s1[j];
        }
        __syncthreads();

        // pointwise cell update (f32): thread (pb,pu2) owns units 2pu2, 2pu2+1
        {
            const int nt = pu2 >> 1;
            const int dq = (2 * pu2) & 3;
            const float* gr = &lds_g[pb][nt * 16];
            const float* br = lds_b[nt];
            float gi0 = sigmoidf_(gr[dq]      + br[dq]);
            float gf0 = sigmoidf_(gr[4 + dq]  + br[4 + dq]);
            float gg0 = tanhf_(   gr[8 + dq]  + br[8 + dq]);
            float go0 = sigmoidf_(gr[12 + dq] + br[12 + dq]);
            c0 = gf0 * c0 + gi0 * gg0;
            float h0v = go0 * tanhf_(c0);
            float gi1 = sigmoidf_(gr[dq + 1]      + br[dq + 1]);
            float gf1 = sigmoidf_(gr[4 + dq + 1]  + br[4 + dq + 1]);
            float gg1 = tanhf_(   gr[8 + dq + 1]  + br[8 + dq + 1]);
            float go1 = sigmoidf_(gr[12 + dq + 1] + br[12 + dq + 1]);
            c1 = gf1 * c1 + gi1 * gg1;
            float h1v = go1 * tanhf_(c1);

            unsigned pack = (unsigned)f2bf(h0v) | ((unsigned)f2bf(h1v) << 16);
            unsigned* yp32 = reinterpret_cast<unsigned*>(ybuf)
                           + ((size_t)t * BATCH + pb) * (HID / 2) + (ubase + 2 * pu2) / 2;
            // relaxed agent atomic store: write-through to coherence point
            __hip_atomic_store(yp32, pack, __ATOMIC_RELAXED, __HIP_MEMORY_SCOPE_AGENT);

            if (t == T_SEQ - 1) {
                hNout[pb * HID + ubase + 2 * pu2]     = h0v;
                hNout[pb * HID + ubase + 2 * pu2 + 1] = h1v;
                cNout[pb * HID + ubase + 2 * pu2]     = c0;
                cNout[pb * HID + ubase + 2 * pu2 + 1] = c1;
            }
        }

        // drain own wave's stores, barrier, then single relaxed flag store
        asm volatile("s_waitcnt vmcnt(0)" ::: "memory");
        __syncthreads();
        if (tid == 0)
            __hip_atomic_store(flags_own + (size_t)g * FLAG_STRIDE, (unsigned)(t + 1),
                               __ATOMIC_RELAXED, __HIP_MEMORY_SCOPE_AGENT);
    }
}

__global__ __launch_bounds__(256, 1)
void lstm_fused(const u16* __restrict__ x_bf,
                const u16* __restrict__ wih0, const u16* __restrict__ whh0, const float* __restrict__ b0,
                const u16* __restrict__ wih1, const u16* __restrict__ whh1, const float* __restrict__ b1,
                u16* __restrict__ y0, u16* __restrict__ y1,
                float* __restrict__ hN, float* __restrict__ cN,
                unsigned* __restrict__ ctr)
{
    __shared__ __align__(16) u16 lds_w[2][32][512];   // 64 KB (L0 uses KS=20 of 32)
    __shared__ float lds_g[BATCH][33];
    __shared__ float lds_b[2][16];

    unsigned* flags0 = ctr;
    unsigned* flags1 = ctr + NWG_L * FLAG_STRIDE;

    const int wgid = blockIdx.x;
    if (wgid < NWG_L) {
        run_layer<0>(x_bf, wih0, whh0, b0, y0, hN, cN,
                     flags0, flags0, wgid, lds_w, lds_g, lds_b);
    } else {
        run_layer<1>(y0, wih1, whh1, b1, y1, hN + BATCH * HID, cN + BATCH * HID,
                     flags1, flags0, wgid - NWG_L, lds_w, lds_g, lds_b);
    }
}

// ---------------- final FC: out[32768,256] = y1[32768,512] @ fc_w[256,512]^T + b ----------
__global__ __launch_bounds__(256)
void fc_kernel(const u16* __restrict__ y1, const u16* __restrict__ fcw,
               const float* __restrict__ fcb, float* __restrict__ out)
{
    const int tid  = threadIdx.x;
    const int lane = tid & 63;
    const int wgid = blockIdx.x * 4 + (tid >> 6);  // 0..1023 waves
    const int nq   = wgid & 3;                     // 64-col block
    const int mt0  = wgid >> 2;                    // 0..255

    for (int j = 0; j < 8; ++j) {
        int mt = mt0 + j * 256;                    // M-tile 0..2047
        f32x4 acc[4] = {{0,0,0,0},{0,0,0,0},{0,0,0,0},{0,0,0,0}};
        const u16* arow = y1 + ((size_t)mt * 16 + (lane & 15)) * HID + (lane >> 4) * 8;
        #pragma unroll
        for (int ks = 0; ks < 16; ++ks) {
            short8 a = *reinterpret_cast<const short8*>(arow + ks * 32);
            #pragma unroll
            for (int nt = 0; nt < 4; ++nt) {
                const u16* brow = fcw + ((size_t)(nq * 64 + nt * 16 + (lane & 15))) * HID
                                      + ks * 32 + (lane >> 4) * 8;
                short8 b = *reinterpret_cast<const short8*>(brow);
                acc[nt] = __builtin_amdgcn_mfma_f32_16x16x32_bf16(a, b, acc[nt], 0, 0, 0);
            }
        }
        #pragma unroll
        for (int nt = 0; nt < 4; ++nt) {
            int col = nq * 64 + nt * 16 + (lane & 15);
            float bb = fcb[col];
            #pragma unroll
            for (int jj = 0; jj < 4; ++jj) {
                int row = mt * 16 + (lane >> 4) * 4 + jj;
                out[(size_t)row * OUTF + col] = acc[nt][jj] + bb;
            }
        }
    }
}

extern "C" void kernel_launch(void* const* d_in, const int* in_sizes, int n_in,
                              void* d_out, int out_size, void* d_ws, size_t ws_size,
                              hipStream_t stream)
{
    const float* x    = (const float*)d_in[0];
    const float* wih0 = (const float*)d_in[1];
    const float* whh0 = (const float*)d_in[2];
    const float* b0   = (const float*)d_in[3];
    const float* wih1 = (const float*)d_in[4];
    const float* whh1 = (const float*)d_in[5];
    const float* b1   = (const float*)d_in[6];
    const float* fcw  = (const float*)d_in[7];
    const float* fcb  = (const float*)d_in[8];
    float* out = (float*)d_out;

    const size_t flag_bytes = (size_t)2 * NWG_L * FLAG_STRIDE * 4;   // 16 KB

    char* ws = (char*)d_ws;
    size_t off = 0;
    unsigned* ctr = (unsigned*)ws;                    off += flag_bytes;
    u16* x_bf    = (u16*)(ws + off);                  off += (size_t)T_SEQ * BATCH * IN0 * 2;
    u16* wih0_bf = (u16*)(ws + off);                  off += (size_t)G4 * IN0 * 2;
    u16* whh0_bf = (u16*)(ws + off);                  off += (size_t)G4 * HID * 2;
    u16* wih1_bf = (u16*)(ws + off);                  off += (size_t)G4 * HID * 2;
    u16* whh1_bf = (u16*)(ws + off);                  off += (size_t)G4 * HID * 2;
    u16* fcw_bf  = (u16*)(ws + off);                  off += (size_t)OUTF * HID * 2;
    u16* y0      = (u16*)(ws + off);                  off += (size_t)T_SEQ * BATCH * HID * 2;
    u16* y1      = (u16*)(ws + off);                  off += (size_t)T_SEQ * BATCH * HID * 2;

    hipMemsetAsync(ctr, 0, flag_bytes, stream);

    auto conv = [&](const float* in, u16* o, int n) {
        int n4 = n / 4;
        cvt_f32_bf16<<<(n4 + 255) / 256, 256, 0, stream>>>(in, o, n4);
    };
    conv(x,    x_bf,    T_SEQ * BATCH * IN0);
    conv(wih0, wih0_bf, G4 * IN0);
    conv(whh0, whh0_bf, G4 * HID);
    conv(wih1, wih1_bf, G4 * HID);
    conv(whh1, whh1_bf, G4 * HID);
    conv(fcw,  fcw_bf,  OUTF * HID);

    float* outFC = out;
    float* hN = out + (size_t)T_SEQ * BATCH * OUTF;     // [2,B,H]
    float* cN = hN + 2 * BATCH * HID;                   // [2,B,H]

    lstm_fused<<<2 * NWG_L, 256, 0, stream>>>(x_bf, wih0_bf, whh0_bf, b0,
                                              wih1_bf, whh1_bf, b1,
                                              y0, y1, hN, cN, ctr);
    fc_kernel<<<256, 256, 0, stream>>>(y1, fcw_bf, fcb, outFC);
}